// Round 17
// baseline (166.250 us; speedup 1.0000x reference)
//
#include <hip/hip_runtime.h>

typedef __attribute__((ext_vector_type(8))) short bf16x8;
typedef __attribute__((ext_vector_type(4))) float f32x4;
typedef __attribute__((ext_vector_type(16))) float f32x16;
typedef __attribute__((ext_vector_type(4))) int i32x4;
using u16 = unsigned short;

constexpr int Bsz = 4, T = 2048, C = 1024, H = 16, Dh = 64;
constexpr int Mrows = Bsz * T;   // 8192
constexpr int K_DIM = 1024;
// scores = (q.k)/sqrt(64); softmax in exp2 domain -> fold (1/8)*log2(e) into Q
constexpr float QSCALE = 0.18033688011112042f;

__device__ inline u16 f2bf(float f) {
    unsigned u = __builtin_bit_cast(unsigned, f);
    u += 0x7FFFu + ((u >> 16) & 1u);
    return (u16)(u >> 16);
}

__device__ inline void g2l16(const void* g, void* l) {
    __builtin_amdgcn_global_load_lds((const __attribute__((address_space(1))) void*)g,
                                     (__attribute__((address_space(3))) void*)l, 16, 0, 0);
}

// pack 2 f32 -> 2 bf16 in one u32 (lo -> low half)
__device__ inline unsigned pk2(float lo, float hi) {
    unsigned d;
    asm("v_cvt_pk_bf16_f32 %0, %1, %2" : "=v"(d) : "v"(lo), "v"(hi));
    return d;
}
// a' = (a.lo32lanes, b.lo32lanes); b' = (a.hi32lanes, b.hi32lanes)
__device__ inline void swap32(unsigned& a, unsigned& b) {
    asm("v_permlane32_swap_b32 %0, %1" : "+v"(a), "+v"(b));
}

// ---------------------------------------------------------------------------
// One-shot f32 -> bf16 conversion of x, w_qkv, w_out (memory-bound, ~14us).
// ---------------------------------------------------------------------------
__global__ __launch_bounds__(256)
void cvt_k(const float* __restrict__ x, const float* __restrict__ wq,
           const float* __restrict__ wo, u16* __restrict__ xb,
           u16* __restrict__ wqb, u16* __restrict__ wob)
{
    int idx = blockIdx.x * 256 + threadIdx.x;
    const float* src; u16* dst; int rel;
    if (idx < 1048576)      { src = x;  dst = xb;  rel = idx; }
    else if (idx < 1441792) { src = wq; dst = wqb; rel = idx - 1048576; }
    else                    { src = wo; dst = wob; rel = idx - 1441792; }
    size_t off = (size_t)rel * 8;
    float4 a = *(const float4*)(src + off);
    float4 b = *(const float4*)(src + off + 4);
    unsigned r0 = (unsigned)f2bf(a.x) | ((unsigned)f2bf(a.y) << 16);
    unsigned r1 = (unsigned)f2bf(a.z) | ((unsigned)f2bf(a.w) << 16);
    unsigned r2 = (unsigned)f2bf(b.x) | ((unsigned)f2bf(b.y) << 16);
    unsigned r3 = (unsigned)f2bf(b.z) | ((unsigned)f2bf(b.w) << 16);
    *(uint4*)(dst + off) = make_uint4(r0, r1, r2, r3);
}

// ---------------------------------------------------------------------------
// 8-phase 256x256 QK-panel GEMM (m201 template port) — r15-verified, ~32us,
// ~1.07 PF. See r15 commentary for the phase/vmcnt schedule derivation.
// ---------------------------------------------------------------------------
__device__ __forceinline__ bf16x8 rdfrag(const u16* base, int row, int kc, int lhi) {
    int byte = row * 128 + kc * 64 + lhi * 16;
    byte ^= (row & 7) << 4;
    return *(const bf16x8*)((const char*)base + byte);
}

__device__ __forceinline__ void stg_half(u16* ldsbase, const u16* gb, int tid) {
    #pragma unroll
    for (int it2 = 0; it2 < 2; ++it2) {
        int i = it2 * 512 + tid;
        int r = i >> 3, c8 = i & 7;
        int sc = c8 ^ (r & 7);   // inverse-swizzled source, linear LDS dest
        g2l16(gb + (size_t)r * K_DIM + sc * 8,
              ldsbase + (size_t)(it2 * 512 + (tid & 448)) * 8);
    }
}

__device__ __forceinline__ void rdAf(bf16x8 (&af)[4][2], const u16* base,
                                     int r0, int lane16, int lhi) {
    #pragma unroll
    for (int mi = 0; mi < 4; ++mi)
        #pragma unroll
        for (int kc = 0; kc < 2; ++kc)
            af[mi][kc] = rdfrag(base, r0 + mi * 16 + lane16, kc, lhi);
}

__device__ __forceinline__ void rdBf(bf16x8 (&bf2)[2][2], const u16* base,
                                     int r0, int lane16, int lhi) {
    #pragma unroll
    for (int ni = 0; ni < 2; ++ni)
        #pragma unroll
        for (int kc = 0; kc < 2; ++kc)
            bf2[ni][kc] = rdfrag(base, r0 + ni * 16 + lane16, kc, lhi);
}

__device__ __forceinline__ void mfma_quad(f32x4 (&acc)[8][4], const bf16x8 (&af)[4][2],
                                          const bf16x8 (&bf2)[2][2], int rh, int ch) {
    #pragma unroll
    for (int kc = 0; kc < 2; ++kc)
        #pragma unroll
        for (int mi = 0; mi < 4; ++mi)
            #pragma unroll
            for (int ni = 0; ni < 2; ++ni)
                acc[rh * 4 + mi][ch * 2 + ni] = __builtin_amdgcn_mfma_f32_16x16x32_bf16(
                    af[mi][kc], bf2[ni][kc], acc[rh * 4 + mi][ch * 2 + ni], 0, 0, 0);
}

__device__ __forceinline__ void ph_open() {
    __builtin_amdgcn_s_barrier();
    asm volatile("s_waitcnt lgkmcnt(0)" ::: "memory");
    __builtin_amdgcn_sched_barrier(0);
}
__device__ __forceinline__ void ph_close() {
    __builtin_amdgcn_s_barrier();
    __builtin_amdgcn_sched_barrier(0);
}

__global__ __launch_bounds__(512, 2)
void gemm_qk8(const u16* __restrict__ xb, const u16* __restrict__ wqkvb,
              u16* __restrict__ qws, u16* __restrict__ kws)
{
    __shared__ alignas(16) u16 As[2][256 * 64];
    __shared__ alignas(16) u16 Bs2[2][256 * 64];

    const int tid = threadIdx.x;
    const int l = tid & 63, wid = tid >> 6;
    const int wm = wid >> 2, wn = wid & 3;
    const int lane16 = l & 15, lhi = l >> 4;
    const int m0 = blockIdx.x * 256, n0 = blockIdx.y * 256;

    const u16* Ab = xb + (size_t)m0 * K_DIM;
    const u16* Bb = wqkvb + (size_t)n0 * K_DIM;

    f32x4 acc[8][4] = {};
    bf16x8 af[4][2];          // current row-half A frags
    bf16x8 bfr[2][2][2];      // [ch][ni][kc] — both col-halves held

    // prologue: tile0 {A0,A1,B0,B1} + tile1 {B0}; gate tile0 with vmcnt(2)
    stg_half(&As[0][0],     Ab, tid);
    stg_half(&As[0][8192],  Ab + (size_t)128 * K_DIM, tid);
    stg_half(&Bs2[0][0],    Bb, tid);
    stg_half(&Bs2[0][8192], Bb + (size_t)128 * K_DIM, tid);
    stg_half(&Bs2[1][0],    Bb + 64, tid);
    asm volatile("s_waitcnt vmcnt(2)" ::: "memory");
    __builtin_amdgcn_s_barrier();
    __builtin_amdgcn_sched_barrier(0);

    for (int it = 0; it < 8; ++it) {
        const int ka = it * 128;          // K byte-col of tile 2it (u16 units)
        const bool more = (it < 7);

        // ---- phase 1: reads A[rh0]+B[ch0] of even buf; stage B1(2it+1) ----
        rdAf(af, As[0], wm * 128, lane16, lhi);
        rdBf(bfr[0], Bs2[0], wn * 64, lane16, lhi);
        stg_half(&Bs2[1][8192], Bb + (size_t)128 * K_DIM + ka + 64, tid);
        ph_open();
        __builtin_amdgcn_s_setprio(1);
        mfma_quad(acc, af, bfr[0], 0, 0);
        __builtin_amdgcn_s_setprio(0);
        ph_close();

        // ---- phase 2: reads B[ch1]; stage A0(2it+1) ----
        rdBf(bfr[1], Bs2[0], wn * 64 + 32, lane16, lhi);
        stg_half(&As[1][0], Ab + ka + 64, tid);
        ph_open();
        __builtin_amdgcn_s_setprio(1);
        mfma_quad(acc, af, bfr[1], 0, 1);
        __builtin_amdgcn_s_setprio(0);
        ph_close();

        // ---- phase 3: reads A[rh1]; stage A1(2it+1) ----
        rdAf(af, As[0], wm * 128 + 64, lane16, lhi);
        stg_half(&As[1][8192], Ab + (size_t)128 * K_DIM + ka + 64, tid);
        ph_open();
        __builtin_amdgcn_s_setprio(1);
        mfma_quad(acc, af, bfr[1], 1, 1);
        __builtin_amdgcn_s_setprio(0);
        ph_close();

        // ---- phase 4: no reads; stage B0(2it+2); vmcnt gates tile 2it+1 ----
        if (more) stg_half(&Bs2[0][0], Bb + ka + 128, tid);
        ph_open();
        __builtin_amdgcn_s_setprio(1);
        mfma_quad(acc, af, bfr[0], 1, 0);
        __builtin_amdgcn_s_setprio(0);
        if (more) asm volatile("s_waitcnt vmcnt(2)" ::: "memory");
        else      asm volatile("s_waitcnt vmcnt(0)" ::: "memory");
        ph_close();

        // ---- phase 5: reads A[rh0]+B[ch0] of odd buf; stage B1(2it+2) ----
        rdAf(af, As[1], wm * 128, lane16, lhi);
        rdBf(bfr[0], Bs2[1], wn * 64, lane16, lhi);
        if (more) stg_half(&Bs2[0][8192], Bb + (size_t)128 * K_DIM + ka + 128, tid);
        ph_open();
        __builtin_amdgcn_s_setprio(1);
        mfma_quad(acc, af, bfr[0], 0, 0);
        __builtin_amdgcn_s_setprio(0);
        ph_close();

        // ---- phase 6: reads B[ch1]; stage A0(2it+2) ----
        rdBf(bfr[1], Bs2[1], wn * 64 + 32, lane16, lhi);
        if (more) stg_half(&As[0][0], Ab + ka + 128, tid);
        ph_open();
        __builtin_amdgcn_s_setprio(1);
        mfma_quad(acc, af, bfr[1], 0, 1);
        __builtin_amdgcn_s_setprio(0);
        ph_close();

        // ---- phase 7: reads A[rh1]; stage A1(2it+2) ----
        rdAf(af, As[1], wm * 128 + 64, lane16, lhi);
        if (more) stg_half(&As[0][8192], Ab + (size_t)128 * K_DIM + ka + 128, tid);
        ph_open();
        __builtin_amdgcn_s_setprio(1);
        mfma_quad(acc, af, bfr[1], 1, 1);
        __builtin_amdgcn_s_setprio(0);
        ph_close();

        // ---- phase 8: no reads; stage B0(2it+3); vmcnt gates tile 2it+2 ----
        if (more) stg_half(&Bs2[1][0], Bb + ka + 192, tid);
        ph_open();
        __builtin_amdgcn_s_setprio(1);
        mfma_quad(acc, af, bfr[0], 1, 0);
        __builtin_amdgcn_s_setprio(0);
        if (more) asm volatile("s_waitcnt vmcnt(2)" ::: "memory");
        else      asm volatile("s_waitcnt vmcnt(0)" ::: "memory");
        ph_close();
    }

    // ---- epilogue: Q/K split, Q pre-scaled ----
    #pragma unroll
    for (int a = 0; a < 8; ++a)
        #pragma unroll
        for (int bc = 0; bc < 4; ++bc)
            #pragma unroll
            for (int r = 0; r < 4; ++r) {
                int gm = m0 + wm * 128 + a * 16 + lhi * 4 + r;
                int gn = n0 + wn * 64 + bc * 16 + lane16;
                float val = acc[a][bc][r];
                int hh = (gn >> 6) & 15, d = gn & 63;
                int bb = gm >> 11, t = gm & 2047;
                size_t off = (((size_t)bb * H + hh) * T + t) * Dh + d;
                if (gn < C) qws[off] = f2bf(val * QSCALE);
                else        kws[off] = f2bf(val);
            }
}

// ---------------------------------------------------------------------------
// m97-structure GEMM body (known-good): 128x128 tile, BK=64, 4 waves,
// global_load_lds staging, 2-barrier K-loop. Used for V panel (MODE 2,
// swapped mfma -> V^T) and out-proj (MODE 1).
// ---------------------------------------------------------------------------
__device__ inline void stage_g(u16* lds, const u16* gb, int ldg, int tid) {
    #pragma unroll
    for (int i = 0; i < 4; ++i) {
        int ch = i * 256 + tid;
        int r = ch >> 3, c8 = ch & 7;
        int sc = c8 ^ (r & 7);   // inverse-swizzled source, linear LDS dest
        g2l16(gb + (size_t)r * ldg + sc * 8, lds + (i * 256 + (tid & 192)) * 8);
    }
}

template<int MODE>
__device__ __forceinline__
void gemm_body(const u16* __restrict__ Ab, const u16* __restrict__ Bb,
               float* __restrict__ Op, u16* __restrict__ vtws,
               u16* As, u16* Bs, int m0, int n0)
{
    const int tid = threadIdx.x;
    const int l = tid & 63, wid = tid >> 6;
    const int wm = wid >> 1, wn = wid & 1;
    const int lane16 = l & 15, lhi = l >> 4;

    const u16* Abase = Ab + (size_t)m0 * K_DIM;
    const u16* Bbase = Bb + (size_t)n0 * K_DIM;

    f32x4 acc[4][4] = {};

    for (int ks = 0; ks < K_DIM / 64; ++ks) {
        __syncthreads();                       // previous compute done, LDS free
        stage_g(As, Abase + ks * 64, K_DIM, tid);
        stage_g(Bs, Bbase + ks * 64, K_DIM, tid);
        __syncthreads();                       // drains vmcnt(0): tiles visible
        #pragma unroll
        for (int kc = 0; kc < 2; kc++) {
            bf16x8 af[4], bfr[4];
            #pragma unroll
            for (int mi = 0; mi < 4; mi++) {
                int row = wm * 64 + mi * 16 + lane16;
                int byte = row * 128 + kc * 64 + lhi * 16; byte ^= (row & 7) << 4;
                af[mi] = *(const bf16x8*)((const char*)As + byte);
            }
            #pragma unroll
            for (int ni = 0; ni < 4; ni++) {
                int row = wn * 64 + ni * 16 + lane16;
                int byte = row * 128 + kc * 64 + lhi * 16; byte ^= (row & 7) << 4;
                bfr[ni] = *(const bf16x8*)((const char*)Bs + byte);
            }
            #pragma unroll
            for (int mi = 0; mi < 4; mi++)
                #pragma unroll
                for (int ni = 0; ni < 4; ni++) {
                    if constexpr (MODE == 2)
                        acc[mi][ni] = __builtin_amdgcn_mfma_f32_16x16x32_bf16(
                            bfr[ni], af[mi], acc[mi][ni], 0, 0, 0);
                    else
                        acc[mi][ni] = __builtin_amdgcn_mfma_f32_16x16x32_bf16(
                            af[mi], bfr[ni], acc[mi][ni], 0, 0, 0);
                }
        }
    }

    if constexpr (MODE == 2) {
        // D layout: regs = W rows (out-features), lanes = x rows (t)
        #pragma unroll
        for (int mi = 0; mi < 4; mi++)
            #pragma unroll
            for (int ni = 0; ni < 4; ni++)
                #pragma unroll
                for (int r = 0; r < 4; r++) {
                    int wr = n0 + wn * 64 + ni * 16 + lhi * 4 + r;  // 2048..3071
                    int tg = m0 + wm * 64 + mi * 16 + lane16;       // 0..8191
                    int hh = (wr >> 6) & 15, d = wr & 63;
                    int bb = tg >> 11, tt = tg & 2047;
                    size_t off = (((size_t)bb * H + hh) * Dh + d) * T + tt;
                    vtws[off] = f2bf(acc[mi][ni][r]);
                }
    } else {
        #pragma unroll
        for (int mi = 0; mi < 4; mi++)
            #pragma unroll
            for (int ni = 0; ni < 4; ni++)
                #pragma unroll
                for (int r = 0; r < 4; r++) {
                    int gm = m0 + wm * 64 + mi * 16 + lhi * 4 + r;
                    int gn = n0 + wn * 64 + ni * 16 + lane16;
                    Op[(size_t)gm * C + gn] = acc[mi][ni][r];
                }
    }
}

__global__ __launch_bounds__(256)
void gemm_v(const u16* __restrict__ xb, const u16* __restrict__ wqkvb,
            u16* __restrict__ vtws)
{
    __shared__ alignas(16) u16 As[128 * 64];
    __shared__ alignas(16) u16 Bs[128 * 64];
    gemm_body<2>(xb, wqkvb, nullptr, vtws, As, Bs,
                 blockIdx.x * 128, 2 * C + blockIdx.y * 128);
}

__global__ __launch_bounds__(256)
void gemm_out(const u16* __restrict__ ob, const u16* __restrict__ woutb,
              float* __restrict__ Op)
{
    __shared__ alignas(16) u16 As[128 * 64];
    __shared__ alignas(16) u16 Bs[128 * 64];
    gemm_body<1>(ob, woutb, Op, nullptr, As, Bs,
                 blockIdx.x * 128, blockIdx.y * 128);
}

// ---------------------------------------------------------------------------
// Flash attention, causal — r17: 4 waves x 64 q-rows (256-row q-tile).
// K/V fragments are IDENTICAL across waves in the swapped-QK structure, so
// doubling q-rows/wave makes each LDS fragment read feed 2x the MFMA
// (32 MFMA : 16 ds_read_b128 vs 16:16) and halves block-steps (17408->9216):
// LDS-pipe time (~28us, the largest consumer), barriers, staging and FETCH
// all ~halve; MFMA/exp2 totals unchanged. r9's version of this failed via
// 128-thread blocks (occupancy collapse); block stays 256 threads here.
// Grid 512 = 64 heads x 8 tiles, head=bid&63 (XCD-L2), longest-first.
// 3-buf counted vmcnt(4) (stage K/V(t+2) per step), constant-max softmax,
// conflict-free column-chunk LDS. T15 reverted (measured null, r16).
// ---------------------------------------------------------------------------
constexpr float SMAX = 16.0f;

__device__ inline void stage_c(u16* lds, const u16* gb, int rstride, int tid) {
    #pragma unroll
    for (int it = 0; it < 2; ++it) {
        int i = it * 256 + tid;            // lds 16B-chunk index
        int r = i & 63, c8 = i >> 6;       // layout: byte = c8*1024 + r*16
        g2l16(gb + (size_t)r * rstride + c8 * 8, lds + i * 8);
    }
}

__global__ __launch_bounds__(256, 2)
void attn_k(const u16* __restrict__ qws, const u16* __restrict__ kws,
            const u16* __restrict__ vtws, u16* __restrict__ ows)
{
    __shared__ alignas(16) u16 KL[3][64 * 64];
    __shared__ alignas(16) u16 VL[3][64 * 64];

    const int bid = blockIdx.x;
    const int head = bid & 63;            // XCD = bid%8 = head%8 (L2 locality)
    const int qt = 7 - (bid >> 6);        // longest q-tiles dispatched first
    const int b = head >> 4, h = head & 15;
    const int tid = threadIdx.x, w = tid >> 6, l = tid & 63;
    const int l31 = l & 31, hi = l >> 5;

    const size_t hoff = (size_t)head * (T * Dh);
    const u16* Qg  = qws + hoff;
    const u16* Kg  = kws + hoff;
    const u16* Vtg = vtws + hoff;   // [Dh][T] per head

    const int qb = qt * 256;
    const int nt = 4 * qt + 4;
    const int qbw = qb + w * 64;          // this wave's 64 q rows

    // Q fragments for both 32-row halves (B-operand: row q = l&31, k = hi*8+j)
    bf16x8 qf[2][4];
    #pragma unroll
    for (int q2 = 0; q2 < 2; ++q2)
        #pragma unroll
        for (int c = 0; c < 4; ++c)
            qf[q2][c] = *(const bf16x8*)(Qg + (size_t)(qbw + q2 * 32 + l31) * Dh
                                         + c * 16 + hi * 8);

    f32x16 oq[2][2] = {};                 // [q2][d-half]
    float lrun[2] = {0.f, 0.f};

    // prologue: stage tiles 0 and 1 (nt >= 4 always) -> 8 loads/thread fly
    stage_c(KL[0], Kg, Dh, tid);
    stage_c(VL[0], Vtg, T, tid);
    stage_c(KL[1], Kg + (size_t)64 * Dh, Dh, tid);
    stage_c(VL[1], Vtg + 64, T, tid);

    int cur = 0;
    for (int t = 0; t < nt; ++t) {
        // tile t ready when <=4 outstanding (t+1's 4 stay in flight)
        if (t + 1 < nt) asm volatile("s_waitcnt vmcnt(4)" ::: "memory");
        else            asm volatile("s_waitcnt vmcnt(0)" ::: "memory");
        __builtin_amdgcn_s_barrier();
        __builtin_amdgcn_sched_barrier(0);

        int nx = cur + 2; if (nx >= 3) nx -= 3;
        if (t + 2 < nt) {                 // stage tile t+2 (buffer read at t-1)
            stage_c(KL[nx], Kg + (size_t)(t + 2) * 64 * Dh, Dh, tid);
            stage_c(VL[nx], Vtg + (t + 2) * 64, T, tid);
        }

        const int kv0 = t * 64;
        if (kv0 <= qbw + 63) {            // wave has unmasked work
            const char* Kb = (const char*)KL[cur];
            const char* Vb = (const char*)VL[cur];

            // K and V frags, shared by both q2 halves (conflict-free reads)
            bf16x8 kf0[4], kf1[4], vf0[4], vf1[4];
            #pragma unroll
            for (int c = 0; c < 4; ++c) {
                int off = (c * 2 + hi) * 1024 + l31 * 16;
                kf0[c] = *(const bf16x8*)(Kb + off);
                kf1[c] = *(const bf16x8*)(Kb + off + 512);
                vf0[c] = *(const bf16x8*)(Vb + off);
                vf1[c] = *(const bf16x8*)(Vb + off + 512);
            }

            #pragma unroll
            for (int q2 = 0; q2 < 2; ++q2) {
                const int qbb = qbw + q2 * 32;
                if (kv0 > qbb + 31) continue;     // this half fully masked

                f32x16 s0{}, s1{};
                __builtin_amdgcn_s_setprio(1);
                #pragma unroll
                for (int c = 0; c < 4; ++c) {
                    s0 = __builtin_amdgcn_mfma_f32_32x32x16_bf16(kf0[c], qf[q2][c], s0, 0, 0, 0);
                    s1 = __builtin_amdgcn_mfma_f32_32x32x16_bf16(kf1[c], qf[q2][c], s1, 0, 0, 0);
                }
                __builtin_amdgcn_s_setprio(0);

                if (kv0 + 63 > qbb) {             // diagonal: causal mask
                    int qg = qbb + l31;
                    #pragma unroll
                    for (int r = 0; r < 16; ++r) {
                        int kvg = kv0 + (r & 3) + 8 * (r >> 2) + 4 * hi;
                        if (kvg > qg)      s0[r] = -__builtin_inff();
                        if (kvg + 32 > qg) s1[r] = -__builtin_inff();
                    }
                }

                // ---- constant-max softmax: p = exp2(s - SMAX) ----
                float p0[16], p1[16];
                float t0 = 0.f, t1 = 0.f, t2 = 0.f, t3 = 0.f;
                #pragma unroll
                for (int r = 0; r < 16; ++r) {
                    p0[r] = __builtin_amdgcn_exp2f(s0[r] - SMAX);
                    p1[r] = __builtin_amdgcn_exp2f(s1[r] - SMAX);
                    float s = p0[r] + p1[r];
                    if ((r & 3) == 0) t0 += s; else if ((r & 3) == 1) t1 += s;
                    else if ((r & 3) == 2) t2 += s; else t3 += s;
                }
                lrun[q2] += (t0 + t1) + (t2 + t3);

                // ---- P -> bf16 A-frags (T12: cvt_pk + permlane32_swap) ----
                unsigned paf[4][4];
                unsigned cc[8];
                #pragma unroll
                for (int i = 0; i < 4; ++i) cc[i]     = pk2(p0[2 * i], p0[2 * i + 1]);
                #pragma unroll
                for (int i = 0; i < 4; ++i) cc[4 + i] = pk2(p0[8 + 2 * i], p0[9 + 2 * i]);
                swap32(cc[0], cc[2]); swap32(cc[1], cc[3]);
                swap32(cc[4], cc[6]); swap32(cc[5], cc[7]);
                #pragma unroll
                for (int i = 0; i < 4; ++i) { paf[0][i] = cc[i]; paf[1][i] = cc[4 + i]; }
                #pragma unroll
                for (int i = 0; i < 4; ++i) cc[i]     = pk2(p1[2 * i], p1[2 * i + 1]);
                #pragma unroll
                for (int i = 0; i < 4; ++i) cc[4 + i] = pk2(p1[8 + 2 * i], p1[9 + 2 * i]);
                swap32(cc[0], cc[2]); swap32(cc[1], cc[3]);
                swap32(cc[4], cc[6]); swap32(cc[5], cc[7]);
                #pragma unroll
                for (int i = 0; i < 4; ++i) { paf[2][i] = cc[i]; paf[3][i] = cc[4 + i]; }

                // ---- O += P V ----
                __builtin_amdgcn_s_setprio(1);
                #pragma unroll
                for (int kb = 0; kb < 4; ++kb) {
                    i32x4 wv = {(int)paf[kb][0], (int)paf[kb][1],
                                (int)paf[kb][2], (int)paf[kb][3]};
                    bf16x8 pa = __builtin_bit_cast(bf16x8, wv);
                    oq[q2][0] = __builtin_amdgcn_mfma_f32_32x32x16_bf16(pa, vf0[kb], oq[q2][0], 0, 0, 0);
                    oq[q2][1] = __builtin_amdgcn_mfma_f32_32x32x16_bf16(pa, vf1[kb], oq[q2][1], 0, 0, 0);
                }
                __builtin_amdgcn_s_setprio(0);
            }
        }
        cur = (cur == 2) ? 0 : cur + 1;
    }

    // ---- finalize ----
    #pragma unroll
    for (int q2 = 0; q2 < 2; ++q2) {
        float lt = lrun[q2] + __shfl_xor(lrun[q2], 32);
        float inv = 1.0f / lt;
        #pragma unroll
        for (int r = 0; r < 16; ++r) {
            int cr = (r & 3) + 8 * (r >> 2) + 4 * hi;
            float il = __shfl(inv, cr);
            size_t rowoff = ((size_t)b * T + qbw + q2 * 32 + cr) * C + h * Dh + l31;
            ows[rowoff]      = f2bf(oq[q2][0][r] * il);
            ows[rowoff + 32] = f2bf(oq[q2][1][r] * il);
        }
    }
}

// ---------------------------------------------------------------------------
extern "C" void kernel_launch(void* const* d_in, const int* in_sizes, int n_in,
                              void* d_out, int out_size, void* d_ws, size_t ws_size,
                              hipStream_t stream)
{
    const float* x     = (const float*)d_in[0];
    const float* w_qkv = (const float*)d_in[1];
    const float* w_out = (const float*)d_in[2];
    float* out = (float*)d_out;

    const size_t SZ = (size_t)Bsz * H * T * Dh;  // 8388608 elems per tensor
    u16* qws   = (u16*)d_ws;
    u16* kws   = qws + SZ;
    u16* vtws  = kws + SZ;        // V transposed: [B][H][Dh][T]
    u16* xb    = vtws + SZ;       // x as bf16; ALIASED with ows (x consumed
    u16* ows   = xb;              //   by the QKV gemms before attn writes ows)
    u16* wqkvb = xb + SZ;         // w_qkv bf16 (3072x1024)
    u16* woutb = wqkvb + (size_t)3 * C * C;  // w_out bf16 (1024x1024)

    cvt_k<<<dim3(6144), 256, 0, stream>>>(x, w_qkv, w_out, xb, wqkvb, woutb);

    // QK panel: 8-phase 256x256, 256 blocks = exactly 1/CU, one round
    gemm_qk8<<<dim3(Mrows / 256, (2 * C) / 256), 512, 0, stream>>>(xb, wqkvb, qws, kws);
    // V panel: m97 128x128 (known-good)
    gemm_v<<<dim3(Mrows / 128, C / 128), 256, 0, stream>>>(xb, wqkvb, vtws);

    attn_k<<<dim3(512), 256, 0, stream>>>(qws, kws, vtws, ows);

    gemm_out<<<dim3(Mrows / 128, C / 128), 256, 0, stream>>>(ows, woutb, out);
}

// Round 18
// 154.600 us; speedup vs baseline: 1.0754x; 1.0754x over previous
//
#include <hip/hip_runtime.h>

typedef __attribute__((ext_vector_type(8))) short bf16x8;
typedef __attribute__((ext_vector_type(4))) float f32x4;
typedef __attribute__((ext_vector_type(16))) float f32x16;
typedef __attribute__((ext_vector_type(4))) int i32x4;
using u16 = unsigned short;

constexpr int Bsz = 4, T = 2048, C = 1024, H = 16, Dh = 64;
constexpr int Mrows = Bsz * T;   // 8192
constexpr int K_DIM = 1024;
// scores = (q.k)/sqrt(64); softmax in exp2 domain -> fold (1/8)*log2(e) into Q
constexpr float QSCALE = 0.18033688011112042f;

__device__ inline u16 f2bf(float f) {
    unsigned u = __builtin_bit_cast(unsigned, f);
    u += 0x7FFFu + ((u >> 16) & 1u);
    return (u16)(u >> 16);
}

__device__ inline void g2l16(const void* g, void* l) {
    __builtin_amdgcn_global_load_lds((const __attribute__((address_space(1))) void*)g,
                                     (__attribute__((address_space(3))) void*)l, 16, 0, 0);
}

// pack 2 f32 -> 2 bf16 in one u32 (lo -> low half)
__device__ inline unsigned pk2(float lo, float hi) {
    unsigned d;
    asm("v_cvt_pk_bf16_f32 %0, %1, %2" : "=v"(d) : "v"(lo), "v"(hi));
    return d;
}
// a' = (a.lo32lanes, b.lo32lanes); b' = (a.hi32lanes, b.hi32lanes)
__device__ inline void swap32(unsigned& a, unsigned& b) {
    asm("v_permlane32_swap_b32 %0, %1" : "+v"(a), "+v"(b));
}

// ---------------------------------------------------------------------------
// One-shot f32 -> bf16 conversion of x, w_qkv, w_out (memory-bound, ~14us).
// ---------------------------------------------------------------------------
__global__ __launch_bounds__(256)
void cvt_k(const float* __restrict__ x, const float* __restrict__ wq,
           const float* __restrict__ wo, u16* __restrict__ xb,
           u16* __restrict__ wqb, u16* __restrict__ wob)
{
    int idx = blockIdx.x * 256 + threadIdx.x;
    const float* src; u16* dst; int rel;
    if (idx < 1048576)      { src = x;  dst = xb;  rel = idx; }
    else if (idx < 1441792) { src = wq; dst = wqb; rel = idx - 1048576; }
    else                    { src = wo; dst = wob; rel = idx - 1441792; }
    size_t off = (size_t)rel * 8;
    float4 a = *(const float4*)(src + off);
    float4 b = *(const float4*)(src + off + 4);
    unsigned r0 = (unsigned)f2bf(a.x) | ((unsigned)f2bf(a.y) << 16);
    unsigned r1 = (unsigned)f2bf(a.z) | ((unsigned)f2bf(a.w) << 16);
    unsigned r2 = (unsigned)f2bf(b.x) | ((unsigned)f2bf(b.y) << 16);
    unsigned r3 = (unsigned)f2bf(b.z) | ((unsigned)f2bf(b.w) << 16);
    *(uint4*)(dst + off) = make_uint4(r0, r1, r2, r3);
}

// ---------------------------------------------------------------------------
// 8-phase 256x256 QK-panel GEMM (m201 template port) — r15-verified, ~32us,
// ~1.07 PF. See r15 commentary for the phase/vmcnt schedule derivation.
// ---------------------------------------------------------------------------
__device__ __forceinline__ bf16x8 rdfrag(const u16* base, int row, int kc, int lhi) {
    int byte = row * 128 + kc * 64 + lhi * 16;
    byte ^= (row & 7) << 4;
    return *(const bf16x8*)((const char*)base + byte);
}

__device__ __forceinline__ void stg_half(u16* ldsbase, const u16* gb, int tid) {
    #pragma unroll
    for (int it2 = 0; it2 < 2; ++it2) {
        int i = it2 * 512 + tid;
        int r = i >> 3, c8 = i & 7;
        int sc = c8 ^ (r & 7);   // inverse-swizzled source, linear LDS dest
        g2l16(gb + (size_t)r * K_DIM + sc * 8,
              ldsbase + (size_t)(it2 * 512 + (tid & 448)) * 8);
    }
}

__device__ __forceinline__ void rdAf(bf16x8 (&af)[4][2], const u16* base,
                                     int r0, int lane16, int lhi) {
    #pragma unroll
    for (int mi = 0; mi < 4; ++mi)
        #pragma unroll
        for (int kc = 0; kc < 2; ++kc)
            af[mi][kc] = rdfrag(base, r0 + mi * 16 + lane16, kc, lhi);
}

__device__ __forceinline__ void rdBf(bf16x8 (&bf2)[2][2], const u16* base,
                                     int r0, int lane16, int lhi) {
    #pragma unroll
    for (int ni = 0; ni < 2; ++ni)
        #pragma unroll
        for (int kc = 0; kc < 2; ++kc)
            bf2[ni][kc] = rdfrag(base, r0 + ni * 16 + lane16, kc, lhi);
}

__device__ __forceinline__ void mfma_quad(f32x4 (&acc)[8][4], const bf16x8 (&af)[4][2],
                                          const bf16x8 (&bf2)[2][2], int rh, int ch) {
    #pragma unroll
    for (int kc = 0; kc < 2; ++kc)
        #pragma unroll
        for (int mi = 0; mi < 4; ++mi)
            #pragma unroll
            for (int ni = 0; ni < 2; ++ni)
                acc[rh * 4 + mi][ch * 2 + ni] = __builtin_amdgcn_mfma_f32_16x16x32_bf16(
                    af[mi][kc], bf2[ni][kc], acc[rh * 4 + mi][ch * 2 + ni], 0, 0, 0);
}

__device__ __forceinline__ void ph_open() {
    __builtin_amdgcn_s_barrier();
    asm volatile("s_waitcnt lgkmcnt(0)" ::: "memory");
    __builtin_amdgcn_sched_barrier(0);
}
__device__ __forceinline__ void ph_close() {
    __builtin_amdgcn_s_barrier();
    __builtin_amdgcn_sched_barrier(0);
}

__global__ __launch_bounds__(512, 2)
void gemm_qk8(const u16* __restrict__ xb, const u16* __restrict__ wqkvb,
              u16* __restrict__ qws, u16* __restrict__ kws)
{
    __shared__ alignas(16) u16 As[2][256 * 64];
    __shared__ alignas(16) u16 Bs2[2][256 * 64];

    const int tid = threadIdx.x;
    const int l = tid & 63, wid = tid >> 6;
    const int wm = wid >> 2, wn = wid & 3;
    const int lane16 = l & 15, lhi = l >> 4;
    const int m0 = blockIdx.x * 256, n0 = blockIdx.y * 256;

    const u16* Ab = xb + (size_t)m0 * K_DIM;
    const u16* Bb = wqkvb + (size_t)n0 * K_DIM;

    f32x4 acc[8][4] = {};
    bf16x8 af[4][2];          // current row-half A frags
    bf16x8 bfr[2][2][2];      // [ch][ni][kc] — both col-halves held

    // prologue: tile0 {A0,A1,B0,B1} + tile1 {B0}; gate tile0 with vmcnt(2)
    stg_half(&As[0][0],     Ab, tid);
    stg_half(&As[0][8192],  Ab + (size_t)128 * K_DIM, tid);
    stg_half(&Bs2[0][0],    Bb, tid);
    stg_half(&Bs2[0][8192], Bb + (size_t)128 * K_DIM, tid);
    stg_half(&Bs2[1][0],    Bb + 64, tid);
    asm volatile("s_waitcnt vmcnt(2)" ::: "memory");
    __builtin_amdgcn_s_barrier();
    __builtin_amdgcn_sched_barrier(0);

    for (int it = 0; it < 8; ++it) {
        const int ka = it * 128;          // K byte-col of tile 2it (u16 units)
        const bool more = (it < 7);

        // ---- phase 1: reads A[rh0]+B[ch0] of even buf; stage B1(2it+1) ----
        rdAf(af, As[0], wm * 128, lane16, lhi);
        rdBf(bfr[0], Bs2[0], wn * 64, lane16, lhi);
        stg_half(&Bs2[1][8192], Bb + (size_t)128 * K_DIM + ka + 64, tid);
        ph_open();
        __builtin_amdgcn_s_setprio(1);
        mfma_quad(acc, af, bfr[0], 0, 0);
        __builtin_amdgcn_s_setprio(0);
        ph_close();

        // ---- phase 2: reads B[ch1]; stage A0(2it+1) ----
        rdBf(bfr[1], Bs2[0], wn * 64 + 32, lane16, lhi);
        stg_half(&As[1][0], Ab + ka + 64, tid);
        ph_open();
        __builtin_amdgcn_s_setprio(1);
        mfma_quad(acc, af, bfr[1], 0, 1);
        __builtin_amdgcn_s_setprio(0);
        ph_close();

        // ---- phase 3: reads A[rh1]; stage A1(2it+1) ----
        rdAf(af, As[0], wm * 128 + 64, lane16, lhi);
        stg_half(&As[1][8192], Ab + (size_t)128 * K_DIM + ka + 64, tid);
        ph_open();
        __builtin_amdgcn_s_setprio(1);
        mfma_quad(acc, af, bfr[1], 1, 1);
        __builtin_amdgcn_s_setprio(0);
        ph_close();

        // ---- phase 4: no reads; stage B0(2it+2); vmcnt gates tile 2it+1 ----
        if (more) stg_half(&Bs2[0][0], Bb + ka + 128, tid);
        ph_open();
        __builtin_amdgcn_s_setprio(1);
        mfma_quad(acc, af, bfr[0], 1, 0);
        __builtin_amdgcn_s_setprio(0);
        if (more) asm volatile("s_waitcnt vmcnt(2)" ::: "memory");
        else      asm volatile("s_waitcnt vmcnt(0)" ::: "memory");
        ph_close();

        // ---- phase 5: reads A[rh0]+B[ch0] of odd buf; stage B1(2it+2) ----
        rdAf(af, As[1], wm * 128, lane16, lhi);
        rdBf(bfr[0], Bs2[1], wn * 64, lane16, lhi);
        if (more) stg_half(&Bs2[0][8192], Bb + (size_t)128 * K_DIM + ka + 128, tid);
        ph_open();
        __builtin_amdgcn_s_setprio(1);
        mfma_quad(acc, af, bfr[0], 0, 0);
        __builtin_amdgcn_s_setprio(0);
        ph_close();

        // ---- phase 6: reads B[ch1]; stage A0(2it+2) ----
        rdBf(bfr[1], Bs2[1], wn * 64 + 32, lane16, lhi);
        if (more) stg_half(&As[0][0], Ab + ka + 128, tid);
        ph_open();
        __builtin_amdgcn_s_setprio(1);
        mfma_quad(acc, af, bfr[1], 0, 1);
        __builtin_amdgcn_s_setprio(0);
        ph_close();

        // ---- phase 7: reads A[rh1]; stage A1(2it+2) ----
        rdAf(af, As[1], wm * 128 + 64, lane16, lhi);
        if (more) stg_half(&As[0][8192], Ab + (size_t)128 * K_DIM + ka + 128, tid);
        ph_open();
        __builtin_amdgcn_s_setprio(1);
        mfma_quad(acc, af, bfr[1], 1, 1);
        __builtin_amdgcn_s_setprio(0);
        ph_close();

        // ---- phase 8: no reads; stage B0(2it+3); vmcnt gates tile 2it+2 ----
        if (more) stg_half(&Bs2[1][0], Bb + ka + 192, tid);
        ph_open();
        __builtin_amdgcn_s_setprio(1);
        mfma_quad(acc, af, bfr[0], 1, 0);
        __builtin_amdgcn_s_setprio(0);
        if (more) asm volatile("s_waitcnt vmcnt(2)" ::: "memory");
        else      asm volatile("s_waitcnt vmcnt(0)" ::: "memory");
        ph_close();
    }

    // ---- epilogue: Q/K split, Q pre-scaled ----
    #pragma unroll
    for (int a = 0; a < 8; ++a)
        #pragma unroll
        for (int bc = 0; bc < 4; ++bc)
            #pragma unroll
            for (int r = 0; r < 4; ++r) {
                int gm = m0 + wm * 128 + a * 16 + lhi * 4 + r;
                int gn = n0 + wn * 64 + bc * 16 + lane16;
                float val = acc[a][bc][r];
                int hh = (gn >> 6) & 15, d = gn & 63;
                int bb = gm >> 11, t = gm & 2047;
                size_t off = (((size_t)bb * H + hh) * T + t) * Dh + d;
                if (gn < C) qws[off] = f2bf(val * QSCALE);
                else        kws[off] = f2bf(val);
            }
}

// ---------------------------------------------------------------------------
// m97-structure GEMM body (known-good): 128x128 tile, BK=64, 4 waves,
// global_load_lds staging, 2-barrier K-loop. Used for V panel (MODE 2,
// swapped mfma -> V^T) and out-proj (MODE 1).
// ---------------------------------------------------------------------------
__device__ inline void stage_g(u16* lds, const u16* gb, int ldg, int tid) {
    #pragma unroll
    for (int i = 0; i < 4; ++i) {
        int ch = i * 256 + tid;
        int r = ch >> 3, c8 = ch & 7;
        int sc = c8 ^ (r & 7);   // inverse-swizzled source, linear LDS dest
        g2l16(gb + (size_t)r * ldg + sc * 8, lds + (i * 256 + (tid & 192)) * 8);
    }
}

template<int MODE>
__device__ __forceinline__
void gemm_body(const u16* __restrict__ Ab, const u16* __restrict__ Bb,
               float* __restrict__ Op, u16* __restrict__ vtws,
               u16* As, u16* Bs, int m0, int n0)
{
    const int tid = threadIdx.x;
    const int l = tid & 63, wid = tid >> 6;
    const int wm = wid >> 1, wn = wid & 1;
    const int lane16 = l & 15, lhi = l >> 4;

    const u16* Abase = Ab + (size_t)m0 * K_DIM;
    const u16* Bbase = Bb + (size_t)n0 * K_DIM;

    f32x4 acc[4][4] = {};

    for (int ks = 0; ks < K_DIM / 64; ++ks) {
        __syncthreads();                       // previous compute done, LDS free
        stage_g(As, Abase + ks * 64, K_DIM, tid);
        stage_g(Bs, Bbase + ks * 64, K_DIM, tid);
        __syncthreads();                       // drains vmcnt(0): tiles visible
        #pragma unroll
        for (int kc = 0; kc < 2; kc++) {
            bf16x8 af[4], bfr[4];
            #pragma unroll
            for (int mi = 0; mi < 4; mi++) {
                int row = wm * 64 + mi * 16 + lane16;
                int byte = row * 128 + kc * 64 + lhi * 16; byte ^= (row & 7) << 4;
                af[mi] = *(const bf16x8*)((const char*)As + byte);
            }
            #pragma unroll
            for (int ni = 0; ni < 4; ni++) {
                int row = wn * 64 + ni * 16 + lane16;
                int byte = row * 128 + kc * 64 + lhi * 16; byte ^= (row & 7) << 4;
                bfr[ni] = *(const bf16x8*)((const char*)Bs + byte);
            }
            #pragma unroll
            for (int mi = 0; mi < 4; mi++)
                #pragma unroll
                for (int ni = 0; ni < 4; ni++) {
                    if constexpr (MODE == 2)
                        acc[mi][ni] = __builtin_amdgcn_mfma_f32_16x16x32_bf16(
                            bfr[ni], af[mi], acc[mi][ni], 0, 0, 0);
                    else
                        acc[mi][ni] = __builtin_amdgcn_mfma_f32_16x16x32_bf16(
                            af[mi], bfr[ni], acc[mi][ni], 0, 0, 0);
                }
        }
    }

    if constexpr (MODE == 2) {
        // D layout: regs = W rows (out-features), lanes = x rows (t)
        #pragma unroll
        for (int mi = 0; mi < 4; mi++)
            #pragma unroll
            for (int ni = 0; ni < 4; ni++)
                #pragma unroll
                for (int r = 0; r < 4; r++) {
                    int wr = n0 + wn * 64 + ni * 16 + lhi * 4 + r;  // 2048..3071
                    int tg = m0 + wm * 64 + mi * 16 + lane16;       // 0..8191
                    int hh = (wr >> 6) & 15, d = wr & 63;
                    int bb = tg >> 11, tt = tg & 2047;
                    size_t off = (((size_t)bb * H + hh) * Dh + d) * T + tt;
                    vtws[off] = f2bf(acc[mi][ni][r]);
                }
    } else {
        #pragma unroll
        for (int mi = 0; mi < 4; mi++)
            #pragma unroll
            for (int ni = 0; ni < 4; ni++)
                #pragma unroll
                for (int r = 0; r < 4; r++) {
                    int gm = m0 + wm * 64 + mi * 16 + lhi * 4 + r;
                    int gn = n0 + wn * 64 + ni * 16 + lane16;
                    Op[(size_t)gm * C + gn] = acc[mi][ni][r];
                }
    }
}

__global__ __launch_bounds__(256)
void gemm_v(const u16* __restrict__ xb, const u16* __restrict__ wqkvb,
            u16* __restrict__ vtws)
{
    __shared__ alignas(16) u16 As[128 * 64];
    __shared__ alignas(16) u16 Bs[128 * 64];
    gemm_body<2>(xb, wqkvb, nullptr, vtws, As, Bs,
                 blockIdx.x * 128, 2 * C + blockIdx.y * 128);
}

__global__ __launch_bounds__(256)
void gemm_out(const u16* __restrict__ ob, const u16* __restrict__ woutb,
              float* __restrict__ Op)
{
    __shared__ alignas(16) u16 As[128 * 64];
    __shared__ alignas(16) u16 Bs[128 * 64];
    gemm_body<1>(ob, woutb, Op, nullptr, As, Bs,
                 blockIdx.x * 128, blockIdx.y * 128);
}

// ---------------------------------------------------------------------------
// Flash attention, causal — r15 config (best measured): swapped-QK 32x32,
// constant-max softmax, s_setprio around MFMA clusters, 4 waves x 32 q-rows,
// grid 1024, head = bid&63 (XCD-L2), longest-first, 3-buf counted vmcnt(4),
// conflict-free column-chunk LDS (conflicts 4.3M -> 0, verified).
// r16 (T15 att[2]) and r17 (64 q-rows/wave) both measured worse — this
// structure is a balanced local optimum (MFMA 22%, VALU 36%, LDS ~30%).
// ---------------------------------------------------------------------------
constexpr float SMAX = 16.0f;

__device__ inline void stage_c(u16* lds, const u16* gb, int rstride, int tid) {
    #pragma unroll
    for (int it = 0; it < 2; ++it) {
        int i = it * 256 + tid;            // lds 16B-chunk index
        int r = i & 63, c8 = i >> 6;       // layout: byte = c8*1024 + r*16
        g2l16(gb + (size_t)r * rstride + c8 * 8, lds + i * 8);
    }
}

__global__ __launch_bounds__(256, 3)
void attn_k(const u16* __restrict__ qws, const u16* __restrict__ kws,
            const u16* __restrict__ vtws, u16* __restrict__ ows)
{
    __shared__ alignas(16) u16 KL[3][64 * 64];
    __shared__ alignas(16) u16 VL[3][64 * 64];

    const int bid = blockIdx.x;
    const int head = bid & 63;            // XCD = bid%8 = head%8 (L2 locality)
    const int qt = 15 - (bid >> 6);       // longest q-tiles dispatched first
    const int b = head >> 4, h = head & 15;
    const int tid = threadIdx.x, w = tid >> 6, l = tid & 63;
    const int l31 = l & 31, hi = l >> 5;

    const size_t hoff = (size_t)head * (T * Dh);
    const u16* Qg  = qws + hoff;
    const u16* Kg  = kws + hoff;
    const u16* Vtg = vtws + hoff;   // [Dh][T] per head

    const int qb = qt * 128;
    const int nt = 2 * qt + 2;
    const int qbw = qb + w * 32;          // this wave's 32 q rows

    // Q fragments (B-operand: row q = l&31, k = hi*8+j), issued first so the
    // vmcnt FIFO retires them before the staged prologue loads.
    bf16x8 qf[4];
    #pragma unroll
    for (int c = 0; c < 4; ++c)
        qf[c] = *(const bf16x8*)(Qg + (size_t)(qbw + l31) * Dh + c * 16 + hi * 8);

    f32x16 o0{}, o1{};                    // d 0..31 / 32..63
    float lrun = 0.f;

    // prologue: stage tiles 0 and 1 (nt >= 2 always) -> 8 loads/thread fly
    stage_c(KL[0], Kg, Dh, tid);
    stage_c(VL[0], Vtg, T, tid);
    stage_c(KL[1], Kg + (size_t)64 * Dh, Dh, tid);
    stage_c(VL[1], Vtg + 64, T, tid);

    int cur = 0;
    for (int t = 0; t < nt; ++t) {
        // tile t ready when <=4 outstanding (t+1's 4 stay in flight)
        if (t + 1 < nt) asm volatile("s_waitcnt vmcnt(4)" ::: "memory");
        else            asm volatile("s_waitcnt vmcnt(0)" ::: "memory");
        __builtin_amdgcn_s_barrier();
        __builtin_amdgcn_sched_barrier(0);

        int nx = cur + 2; if (nx >= 3) nx -= 3;
        if (t + 2 < nt) {                 // stage tile t+2 (buffer read at t-1)
            stage_c(KL[nx], Kg + (size_t)(t + 2) * 64 * Dh, Dh, tid);
            stage_c(VL[nx], Vtg + (t + 2) * 64, T, tid);
        }

        const int kv0 = t * 64;
        if (kv0 <= qbw + 31) {            // wave has unmasked work
            const char* Kb = (const char*)KL[cur];
            const char* Vb = (const char*)VL[cur];

            bf16x8 kf0[4], kf1[4];        // A-operand: kv rows 0..31 / 32..63
            #pragma unroll
            for (int c = 0; c < 4; ++c) {
                int off = (c * 2 + hi) * 1024 + l31 * 16;
                kf0[c] = *(const bf16x8*)(Kb + off);
                kf1[c] = *(const bf16x8*)(Kb + off + 512);
            }

            f32x16 s0{}, s1{};
            __builtin_amdgcn_s_setprio(1);
            #pragma unroll
            for (int c = 0; c < 4; ++c) {
                s0 = __builtin_amdgcn_mfma_f32_32x32x16_bf16(kf0[c], qf[c], s0, 0, 0, 0);
                s1 = __builtin_amdgcn_mfma_f32_32x32x16_bf16(kf1[c], qf[c], s1, 0, 0, 0);
            }
            __builtin_amdgcn_s_setprio(0);

            if (kv0 + 63 > qbw) {         // diagonal: causal mask
                int qg = qbw + l31;
                #pragma unroll
                for (int r = 0; r < 16; ++r) {
                    int kvg = kv0 + (r & 3) + 8 * (r >> 2) + 4 * hi;
                    if (kvg > qg)      s0[r] = -__builtin_inff();
                    if (kvg + 32 > qg) s1[r] = -__builtin_inff();
                }
            }

            // ---- constant-max softmax: p = exp2(s - SMAX), no max tracking ----
            float p0[16], p1[16];
            float t0 = 0.f, t1 = 0.f, t2 = 0.f, t3 = 0.f;
            #pragma unroll
            for (int r = 0; r < 16; ++r) {
                p0[r] = __builtin_amdgcn_exp2f(s0[r] - SMAX);
                p1[r] = __builtin_amdgcn_exp2f(s1[r] - SMAX);
                float s = p0[r] + p1[r];
                if ((r & 3) == 0) t0 += s; else if ((r & 3) == 1) t1 += s;
                else if ((r & 3) == 2) t2 += s; else t3 += s;
            }
            lrun += (t0 + t1) + (t2 + t3);

            // ---- P -> bf16 A-frags (T12: cvt_pk + permlane32_swap) ----
            unsigned paf[4][4];
            unsigned cc[8];
            #pragma unroll
            for (int i = 0; i < 4; ++i) cc[i]     = pk2(p0[2 * i], p0[2 * i + 1]);
            #pragma unroll
            for (int i = 0; i < 4; ++i) cc[4 + i] = pk2(p0[8 + 2 * i], p0[9 + 2 * i]);
            swap32(cc[0], cc[2]); swap32(cc[1], cc[3]);
            swap32(cc[4], cc[6]); swap32(cc[5], cc[7]);
            #pragma unroll
            for (int i = 0; i < 4; ++i) { paf[0][i] = cc[i]; paf[1][i] = cc[4 + i]; }
            #pragma unroll
            for (int i = 0; i < 4; ++i) cc[i]     = pk2(p1[2 * i], p1[2 * i + 1]);
            #pragma unroll
            for (int i = 0; i < 4; ++i) cc[4 + i] = pk2(p1[8 + 2 * i], p1[9 + 2 * i]);
            swap32(cc[0], cc[2]); swap32(cc[1], cc[3]);
            swap32(cc[4], cc[6]); swap32(cc[5], cc[7]);
            #pragma unroll
            for (int i = 0; i < 4; ++i) { paf[2][i] = cc[i]; paf[3][i] = cc[4 + i]; }

            // ---- O += P V (conflict-free column-chunk V reads) ----
            __builtin_amdgcn_s_setprio(1);
            #pragma unroll
            for (int kb = 0; kb < 4; ++kb) {
                i32x4 wv = {(int)paf[kb][0], (int)paf[kb][1],
                            (int)paf[kb][2], (int)paf[kb][3]};
                bf16x8 pa = __builtin_bit_cast(bf16x8, wv);
                int off = (kb * 2 + hi) * 1024 + l31 * 16;
                bf16x8 v0 = *(const bf16x8*)(Vb + off);
                bf16x8 v1 = *(const bf16x8*)(Vb + off + 512);
                o0 = __builtin_amdgcn_mfma_f32_32x32x16_bf16(pa, v0, o0, 0, 0, 0);
                o1 = __builtin_amdgcn_mfma_f32_32x32x16_bf16(pa, v1, o1, 0, 0, 0);
            }
            __builtin_amdgcn_s_setprio(0);
        }
        cur = (cur == 2) ? 0 : cur + 1;
    }

    // ---- finalize ----
    float lt = lrun + __shfl_xor(lrun, 32);
    float inv = 1.0f / lt;
    #pragma unroll
    for (int r = 0; r < 16; ++r) {
        int cr = (r & 3) + 8 * (r >> 2) + 4 * hi;
        float il = __shfl(inv, cr);
        size_t rowoff = ((size_t)b * T + qb + w * 32 + cr) * C + h * Dh + l31;
        ows[rowoff]      = f2bf(o0[r] * il);
        ows[rowoff + 32] = f2bf(o1[r] * il);
    }
}

// ---------------------------------------------------------------------------
extern "C" void kernel_launch(void* const* d_in, const int* in_sizes, int n_in,
                              void* d_out, int out_size, void* d_ws, size_t ws_size,
                              hipStream_t stream)
{
    const float* x     = (const float*)d_in[0];
    const float* w_qkv = (const float*)d_in[1];
    const float* w_out = (const float*)d_in[2];
    float* out = (float*)d_out;

    const size_t SZ = (size_t)Bsz * H * T * Dh;  // 8388608 elems per tensor
    u16* qws   = (u16*)d_ws;
    u16* kws   = qws + SZ;
    u16* vtws  = kws + SZ;        // V transposed: [B][H][Dh][T]
    u16* xb    = vtws + SZ;       // x as bf16; ALIASED with ows (x consumed
    u16* ows   = xb;              //   by the QKV gemms before attn writes ows)
    u16* wqkvb = xb + SZ;         // w_qkv bf16 (3072x1024)
    u16* woutb = wqkvb + (size_t)3 * C * C;  // w_out bf16 (1024x1024)

    cvt_k<<<dim3(6144), 256, 0, stream>>>(x, w_qkv, w_out, xb, wqkvb, woutb);

    // QK panel: 8-phase 256x256, 256 blocks = exactly 1/CU, one round
    gemm_qk8<<<dim3(Mrows / 256, (2 * C) / 256), 512, 0, stream>>>(xb, wqkvb, qws, kws);
    // V panel: m97 128x128 (known-good)
    gemm_v<<<dim3(Mrows / 128, C / 128), 256, 0, stream>>>(xb, wqkvb, vtws);

    attn_k<<<dim3(1024), 256, 0, stream>>>(qws, kws, vtws, ows);

    gemm_out<<<dim3(Mrows / 128, C / 128), 256, 0, stream>>>(ows, woutb, out);
}